// Round 5
// baseline (248.350 us; speedup 1.0000x reference)
//
#include <hip/hip_runtime.h>

constexpr int BB   = 4;
constexpr int CCH  = 256;
constexpr int IDIM = 128;
constexpr int NAa  = 4096;
constexpr int NDd  = 16384;
constexpr int PAD  = 320;                 // aug dim 257 padded to 320
constexpr float NAinv = 1.0f / 4096.0f;

typedef __bf16 bf16x8 __attribute__((ext_vector_type(8)));
typedef float  f32x4  __attribute__((ext_vector_type(4)));

__device__ inline unsigned short f2bfu(float f) {
    unsigned u = __float_as_uint(f);
    u += 0x7FFFu + ((u >> 16) & 1u);      // RNE
    return (unsigned short)(u >> 16);
}

// ---- fused front: blocks [0,1024): aim->bf16 + rowsum; [1024,1744): weight prep ----
__global__ __launch_bounds__(256) void k_front(const float* __restrict__ aim,
                                               unsigned short* __restrict__ Abf,
                                               float* __restrict__ r,
                                               const float* __restrict__ qw,
                                               const float* __restrict__ gw,
                                               const float* __restrict__ gb,
                                               const float* __restrict__ thw,
                                               const float* __restrict__ thb,
                                               const float* __restrict__ phw,
                                               const float* __restrict__ phb,
                                               unsigned short* __restrict__ Ph,
                                               unsigned short* __restrict__ Rt) {
    const int t = threadIdx.x;
    if (blockIdx.x < BB * CCH) {
        const int row = blockIdx.x;
        const float* src = aim + (long)row * NAa;
        unsigned short* dst = Abf + (long)row * NAa;
        float s = 0.f;
        #pragma unroll
        for (int j = 0; j < 4; ++j) {
            const int e = (j * 256 + t) * 4;
            float4 v = *(const float4*)(src + e);
            s += v.x + v.y + v.z + v.w;
            ushort4 o; o.x = f2bfu(v.x); o.y = f2bfu(v.y); o.z = f2bfu(v.z); o.w = f2bfu(v.w);
            *(ushort4*)(dst + e) = o;
        }
        __shared__ float red[256];
        red[t] = s; __syncthreads();
        for (int st = 128; st > 0; st >>= 1) { if (t < st) red[t] += red[t + st]; __syncthreads(); }
        if (t == 0) r[row] = red[0];
    } else {
        const int idx = (blockIdx.x - BB * CCH) * 256 + t;
        if (idx < CCH * PAD) {
            const int o = idx / PAD, c = idx - o * PAD;
            float acc = 0.f;
            if (c <= 256) {
                for (int i = 0; i < IDIM; ++i)
                    acc += qw[o * IDIM + i] * ((c < 256) ? gw[i * CCH + c] : gb[i]);
            }
            Ph[idx] = f2bfu(acc);
        } else {
            const int id2 = idx - CCH * PAD;
            const int c2 = id2 / PAD, k = id2 - c2 * PAD;   // RhatT: row c2, col k
            float acc = 0.f;
            if (k <= 256 && c2 <= 256) {
                for (int i = 0; i < IDIM; ++i) {
                    const float av = (k < 256) ? thw[i * CCH + k] : thb[i];
                    const float bv = (c2 < 256) ? phw[i * CCH + c2] : phb[i];
                    acc += av * bv;
                }
            }
            Rt[id2] = f2bfu(acc);
        }
    }
}

// ---- S partials: Spart[z] = A[b] @ A[b]^T over 256-K chunk. grid (4,4,BB*16), block 64 ----
__global__ __launch_bounds__(64) void k_S(const unsigned short* __restrict__ Abf,
                                          float* __restrict__ Spart) {
    const int z = blockIdx.z, b = z >> 4, chunk = z & 15;
    const unsigned short* A = Abf + (long)b * CCH * NAa;
    const int lane = threadIdx.x, quad = lane >> 4, l16 = lane & 15;
    const int mb = blockIdx.y * 64, nb = blockIdx.x * 64;
    const int kb = chunk * 256;
    f32x4 acc[4][4] = {};
    for (int ks = 0; ks < 8; ++ks) {
        const int k = kb + ks * 32 + quad * 8;
        bf16x8 af[4], bfr[4];
        #pragma unroll
        for (int i = 0; i < 4; ++i) af[i]  = *(const bf16x8*)(A + (long)(mb + i * 16 + l16) * NAa + k);
        #pragma unroll
        for (int j = 0; j < 4; ++j) bfr[j] = *(const bf16x8*)(A + (long)(nb + j * 16 + l16) * NAa + k);
        #pragma unroll
        for (int i = 0; i < 4; ++i)
            #pragma unroll
            for (int j = 0; j < 4; ++j)
                acc[i][j] = __builtin_amdgcn_mfma_f32_16x16x32_bf16(af[i], bfr[j], acc[i][j], 0, 0, 0);
    }
    float* o = Spart + (long)z * CCH * CCH;
    #pragma unroll
    for (int i = 0; i < 4; ++i)
        #pragma unroll
        for (int j = 0; j < 4; ++j)
            #pragma unroll
            for (int reg = 0; reg < 4; ++reg)
                o[(long)(mb + i * 16 + quad * 4 + reg) * CCH + nb + j * 16 + l16] = acc[i][j][reg];
}

// ---- assemble Shat (320x320 bf16, symmetric): [[sum Spart, r],[r^T, Na]] ----
__global__ __launch_bounds__(256) void k_red(const float* __restrict__ Spart,
                                             const float* __restrict__ r,
                                             unsigned short* __restrict__ Shat) {
    const int b = blockIdx.y;
    const int idx = blockIdx.x * 256 + threadIdx.x;     // < 320*320
    const int k = idx / PAD, n = idx - k * PAD;
    float v = 0.f;
    if (k < 256 && n < 256) {
        #pragma unroll
        for (int p = 0; p < 16; ++p)
            v += Spart[(long)(b * 16 + p) * CCH * CCH + k * CCH + n];
    } else if (k == 256 && n < 256) v = r[b * CCH + n];
    else if (n == 256 && k < 256)   v = r[b * CCH + k];
    else if (k == 256 && n == 256)  v = 4096.0f;
    Shat[(long)b * PAD * PAD + idx] = f2bfu(v);
}

// ---- fused: That rows = Phat@Shat (to LDS), then W5 rows = diag(s)/Na*(That@Rhat)+I ----
// grid (4 m-tiles, BB), block 256 (4 waves; wave w handles n-tiles {w, w+4})
__global__ __launch_bounds__(256) void k_w5f(const unsigned short* __restrict__ Ph,
                                             const unsigned short* __restrict__ Sh,
                                             const unsigned short* __restrict__ Rt,
                                             const float* __restrict__ qb,
                                             const float* __restrict__ gamma,
                                             const float* __restrict__ beta,
                                             const float* __restrict__ mean,
                                             const float* __restrict__ var,
                                             unsigned short* __restrict__ W5u,
                                             float* __restrict__ b5) {
    const int b = blockIdx.y, m0 = blockIdx.x * 64;
    const unsigned short* S = Sh + (long)b * PAD * PAD;
    const int t = threadIdx.x, w = t >> 6, lane = t & 63, quad = lane >> 4, l16 = lane & 15;
    __shared__ __align__(16) unsigned short Tl[64][PAD];

    for (int nt = w; nt < 5; nt += 4) {
        f32x4 acc[4][4] = {};
        for (int kt = 0; kt < PAD; kt += 32) {
            bf16x8 af[4], bfr[4];
            #pragma unroll
            for (int i = 0; i < 4; ++i)
                af[i]  = *(const bf16x8*)(Ph + (long)(m0 + i * 16 + l16) * PAD + kt + quad * 8);
            #pragma unroll
            for (int j = 0; j < 4; ++j)   // Shat symmetric: B[k][n] = Shat row n
                bfr[j] = *(const bf16x8*)(S + (long)(nt * 64 + j * 16 + l16) * PAD + kt + quad * 8);
            #pragma unroll
            for (int i = 0; i < 4; ++i)
                #pragma unroll
                for (int j = 0; j < 4; ++j)
                    acc[i][j] = __builtin_amdgcn_mfma_f32_16x16x32_bf16(af[i], bfr[j], acc[i][j], 0, 0, 0);
        }
        #pragma unroll
        for (int i = 0; i < 4; ++i)
            #pragma unroll
            for (int j = 0; j < 4; ++j)
                #pragma unroll
                for (int reg = 0; reg < 4; ++reg)
                    Tl[i * 16 + quad * 4 + reg][nt * 64 + j * 16 + l16] = f2bfu(acc[i][j][reg]);
    }
    __syncthreads();
    for (int nt = w; nt < 5; nt += 4) {
        f32x4 acc[4][4] = {};
        for (int kt = 0; kt < PAD; kt += 32) {
            bf16x8 af[4], bfr[4];
            #pragma unroll
            for (int i = 0; i < 4; ++i)
                af[i]  = *(const bf16x8*)(&Tl[i * 16 + l16][kt + quad * 8]);
            #pragma unroll
            for (int j = 0; j < 4; ++j)
                bfr[j] = *(const bf16x8*)(Rt + (long)(nt * 64 + j * 16 + l16) * PAD + kt + quad * 8);
            #pragma unroll
            for (int i = 0; i < 4; ++i)
                #pragma unroll
                for (int j = 0; j < 4; ++j)
                    acc[i][j] = __builtin_amdgcn_mfma_f32_16x16x32_bf16(af[i], bfr[j], acc[i][j], 0, 0, 0);
        }
        #pragma unroll
        for (int i = 0; i < 4; ++i)
            #pragma unroll
            for (int reg = 0; reg < 4; ++reg) {
                const int o = m0 + i * 16 + quad * 4 + reg;
                const float s = gamma[o] * rsqrtf(var[o] + 1e-5f);
                #pragma unroll
                for (int j = 0; j < 4; ++j) {
                    const int c2 = nt * 64 + j * 16 + l16;
                    const float val = acc[i][j][reg] * s * NAinv;
                    if (c2 < CCH)
                        W5u[((long)b * CCH + o) * CCH + c2] = f2bfu(val + (o == c2 ? 1.0f : 0.0f));
                    else if (c2 == CCH)
                        b5[b * CCH + o] = val + s * (qb[o] - mean[o]) + beta[o];
                }
            }
    }
}

// ---- out = W5 @ detect + b5: barrier-free streaming MFMA (no LDS). grid (128,2,BB) ----
__global__ __launch_bounds__(256) void k_final(const float* __restrict__ D0,
                                               const unsigned short* __restrict__ W5u,
                                               const float* __restrict__ b5,
                                               float* __restrict__ out) {
    const int z = blockIdx.z;
    const int nb = blockIdx.x * 128;
    const int ob = blockIdx.y * 128;
    const float* D = D0 + (long)z * CCH * NDd;
    float* O = out + (long)z * CCH * NDd;
    const unsigned short* W = W5u + (long)z * CCH * CCH;
    const int t = threadIdx.x, wv = t >> 6, lane = t & 63, quad = lane >> 4, l16 = lane & 15;
    const int mw = (wv >> 1) * 64, nw = (wv & 1) * 64;
    int nj[4];
    #pragma unroll
    for (int j = 0; j < 4; ++j) nj[j] = nb + nw + j * 16 + l16;

    f32x4 acc[4][4] = {};
    for (int kt = 0; kt < CCH; kt += 32) {
        const float* Dk = D + (long)(kt + quad * 8) * NDd;
        bf16x8 bfr[4];
        #pragma unroll
        for (int j = 0; j < 4; ++j) {     // B-fragment: 8 strided rows, convert in-reg
            float xv[8];
            #pragma unroll
            for (int e = 0; e < 8; ++e) xv[e] = Dk[(long)e * NDd + nj[j]];
            union { unsigned u[4]; bf16x8 v; } pk;
            #pragma unroll
            for (int pp = 0; pp < 4; ++pp)
                pk.u[pp] = (unsigned)f2bfu(xv[2 * pp]) | ((unsigned)f2bfu(xv[2 * pp + 1]) << 16);
            bfr[j] = pk.v;
        }
        bf16x8 af[4];
        #pragma unroll
        for (int i = 0; i < 4; ++i)
            af[i] = *(const bf16x8*)(W + (long)(ob + mw + i * 16 + l16) * CCH + kt + quad * 8);
        #pragma unroll
        for (int i = 0; i < 4; ++i)
            #pragma unroll
            for (int j = 0; j < 4; ++j)
                acc[i][j] = __builtin_amdgcn_mfma_f32_16x16x32_bf16(af[i], bfr[j], acc[i][j], 0, 0, 0);
    }
    #pragma unroll
    for (int i = 0; i < 4; ++i) {
        float bv[4];
        #pragma unroll
        for (int reg = 0; reg < 4; ++reg)
            bv[reg] = b5[z * CCH + ob + mw + i * 16 + quad * 4 + reg];
        #pragma unroll
        for (int j = 0; j < 4; ++j) {
            const int n = nb + nw + j * 16 + l16;
            #pragma unroll
            for (int reg = 0; reg < 4; ++reg)
                O[(long)(ob + mw + i * 16 + quad * 4 + reg) * NDd + n] = acc[i][j][reg] + bv[reg];
        }
    }
}

extern "C" void kernel_launch(void* const* d_in, const int* in_sizes, int n_in,
                              void* d_out, int out_size, void* d_ws, size_t ws_size,
                              hipStream_t stream) {
    const float* detect = (const float*)d_in[0];
    const float* aim    = (const float*)d_in[1];
    const float* g_w    = (const float*)d_in[2];
    const float* g_b    = (const float*)d_in[3];
    const float* th_w   = (const float*)d_in[4];
    const float* th_b   = (const float*)d_in[5];
    const float* phi_w  = (const float*)d_in[6];
    const float* phi_b  = (const float*)d_in[7];
    const float* q_w    = (const float*)d_in[8];
    const float* q_b    = (const float*)d_in[9];
    const float* gamma  = (const float*)d_in[10];
    const float* beta   = (const float*)d_in[11];
    const float* mean   = (const float*)d_in[12];
    const float* var    = (const float*)d_in[13];
    float* out = (float*)d_out;

    float* ws = (float*)d_ws;
    unsigned short* Abf = (unsigned short*)ws;              // 4,194,304 us = 2,097,152 f
    float* r     = ws + 2097152;                            // 1,024
    float* Spart = r + 1024;                                // 16*4*65536 = 4,194,304 f
    unsigned short* ub = (unsigned short*)(Spart + 4194304);
    unsigned short* Shat_u  = ub;                           // 4*320*320 = 409,600 us
    unsigned short* Phat_u  = Shat_u + 409600;              // 256*320   =  81,920 us
    unsigned short* RhatT_u = Phat_u + 81920;               // 320*320   = 102,400 us
    unsigned short* W5u     = RhatT_u + 102400;             // 4*256*256 = 262,144 us
    float* b5 = (float*)(W5u + 262144);                     // 1,024 f

    const int prep_blocks = (CCH * PAD + PAD * PAD) / 256;  // 720
    k_front<<<dim3(BB * CCH + prep_blocks), dim3(256), 0, stream>>>(
        aim, Abf, r, q_w, g_w, g_b, th_w, th_b, phi_w, phi_b, Phat_u, RhatT_u);
    k_S<<<dim3(4, 4, BB * 16), dim3(64), 0, stream>>>(Abf, Spart);
    k_red<<<dim3(PAD * PAD / 256, BB), dim3(256), 0, stream>>>(Spart, r, Shat_u);
    k_w5f<<<dim3(4, BB), dim3(256), 0, stream>>>(
        Phat_u, Shat_u, RhatT_u, q_b, gamma, beta, mean, var, W5u, b5);
    k_final<<<dim3(NDd / 128, CCH / 128, BB), dim3(256), 0, stream>>>(detect, W5u, b5, out);
}